// Round 5
// baseline (473.550 us; speedup 1.0000x reference)
//
#include <hip/hip_runtime.h>
#include <math.h>

#define N_TOK 32768
#define K_CODES 4096
#define DIM 512
#define COMMIT 0.25f
#define NCAND 8
#define NSPLIT 2
#define SPLIT_CODES (K_CODES / NSPLIT)   // 2048
#define NITER (SPLIT_CODES / 256)        // 8 col-iterations of 256 codes
#define BIAS 0.125f

typedef short s16x8 __attribute__((ext_vector_type(8)));
typedef float f32x4 __attribute__((ext_vector_type(4)));
typedef unsigned int uint32;
typedef unsigned long long u64;
typedef unsigned short u16;

__device__ __forceinline__ u16 f2bf(float f) {
    uint32 b = __float_as_uint(f);
    return (u16)((b + 0x7FFFu + ((b >> 16) & 1u)) >> 16);
}

// global -> LDS direct DMA, 16B per lane. LDS dest wave-uniform; HW writes
// lds + lane*16. Source address is per-lane (pre-swizzled).
__device__ __forceinline__ void gload16(const u16* g, u16* l) {
    __builtin_amdgcn_global_load_lds(
        (const __attribute__((address_space(1))) void*)g,
        (__attribute__((address_space(3))) void*)l,
        16, 0, 0);
}

// ---------------------------------------------------------------------------
// fp32 -> bf16 (RNE) bulk convert.
// ---------------------------------------------------------------------------
__global__ __launch_bounds__(256) void tobf16_kernel(const float* __restrict__ src,
                                                     u16* __restrict__ dst, int n4) {
    int i = blockIdx.x * 256 + threadIdx.x;
    int stride = gridDim.x * 256;
    for (; i < n4; i += stride) {
        float4 v = ((const float4*)src)[i];
        ushort4 o;
        o.x = f2bf(v.x); o.y = f2bf(v.y); o.z = f2bf(v.z); o.w = f2bf(v.w);
        ((ushort4*)dst)[i] = o;
    }
}

// ---------------------------------------------------------------------------
// numpy-exact fp32 row sum of squares (pairwise algorithm) — R3-verified.
// ---------------------------------------------------------------------------
__global__ __launch_bounds__(256) void rowsq_np_kernel(const float* __restrict__ a,
                                                       float* __restrict__ out,
                                                       int nrows) {
    #pragma clang fp contract(off)
    const int gw   = (blockIdx.x * 256 + threadIdx.x) >> 6;
    const int lane = threadIdx.x & 63;
    const int row  = gw * 8 + (lane >> 3);
    const int j    = lane & 7;
    if (row >= nrows) return;
    const float* p = a + (size_t)row * DIM;
    float blk[4];
    #pragma unroll
    for (int b = 0; b < 4; ++b) {
        const float* q = p + b * 128;
        float v = q[j];
        float r = v * v;
        for (int i = 8; i < 128; i += 8) { float u = q[i + j]; r += u * u; }
        float s1 = r  + __shfl_xor(r, 1);
        float s2 = s1 + __shfl_xor(s1, 2);
        float s3 = s2 + __shfl_xor(s2, 4);
        blk[b] = s3;
    }
    float res = (blk[0] + blk[1]) + (blk[2] + blk[3]);
    if (j == 0) out[row] = res;
}

// ---------------------------------------------------------------------------
// MFMA bf16 screen, counted-vmcnt pipeline (T3/T4 schedule).
// Block: 512 thr = 8 waves, tile 64 tok x 256 codes/iter; wave tile
// 32 tok x 64 codes (2x4 grid of 16x16x32 MFMA). K chunks BK=64, flattened
// t = it*8+kc (64 chunks). TRIPLE-buffered X (3x8 KiB) + W (3x32 KiB) =
// 120 KiB LDS (empirical budget: 128 KiB/CU -> 1 block, 8 waves).
// Per chunk: ONE raw s_barrier; each wave issues exactly 5 gload_lds for
// chunk t+2; next chunk waits s_waitcnt vmcnt(5) (never 0 until t=63) so
// DMA stays in flight across barriers (m218 counted-vs-drain0 mechanism).
// Race safety: barrier at chunk-top certifies all waves done computing t-1
// before DMA targets buf[(t+2)%3] == buf[(t-1)%3]. w2 terms preloaded into
// registers BEFORE the prologue __syncthreads (whose vmcnt(0) retires them
// for the compiler's waitcnt tracking -> no hidden drains in the loop).
// Screening semantics identical to R4-verified: top-2 per (lane,ti) bucket,
// id=(it<<2)|c, top-6 per token per split, NCAND=8 refine.
// ---------------------------------------------------------------------------
__global__ __launch_bounds__(512, 2) void screen_kernel(const u16* __restrict__ xb,
                                                        const u16* __restrict__ wb,
                                                        const float* __restrict__ w2f,
                                                        u64* __restrict__ candPart) {
    __shared__ __attribute__((aligned(16))) u16 POOL[61440];  // 120 KiB
    // u16 offsets: X bufs {0,4096,8192} (64 rows x 64 dims each),
    //              W bufs {12288,28672,45056} (256 rows x 64 dims each).
    // Merge phase reuses first 64 KiB as 64 tok x 128 u64.

    const int tid  = threadIdx.x;
    const int wv   = tid >> 6;
    const int wt   = wv >> 2;          // token half (0/1), 32 rows each
    const int wc   = wv & 3;           // code column (0..3), 64 codes each
    const int lane = tid & 63;
    const int quad = lane >> 4;
    const int n15  = lane & 15;
    const int m0   = blockIdx.x * 64;
    const int sbase = blockIdx.y * SPLIT_CODES;

    // DMA geometry: 1 instr = 64 lanes x 16B = 8 rows x 8 quanta (128B rows).
    // phys quantum p at row r holds logical p^(r&7); r&7 == lane>>3 for
    // 8-aligned row bases -> src quantum = (lane&7)^(lane>>3).
    const int l8  = lane >> 3;
    const int qsw = (lane & 7) ^ l8;

    // X: 64 rows/chunk, 8 rows per wave -> 1 instr; dims kc*64.
    const u16* xg = xb + (size_t)(m0 + wv * 8 + l8) * DIM + qsw * 8;
    // W: 256 rows/chunk, 32 per wave -> 4 instrs (j*8 rows); dims kc*64.
    const u16* wg = wb + (size_t)(sbase + wv * 32 + l8) * DIM + qsw * 8;

    // wave-uniform LDS staging offsets (u16 units)
    const int xdst = wv * 512;
    const int wdst = wv * 2048;

    // preload w2+BIAS for all its into registers (static: it-loop unrolled).
    // Issued BEFORE __syncthreads -> compiler retires them at the barrier's
    // vmcnt(0); no auto-waits inside the K-loop.
    float w2all[NITER][4];
    #pragma unroll
    for (int it = 0; it < NITER; ++it)
        #pragma unroll
        for (int c = 0; c < 4; ++c)
            w2all[it][c] = w2f[sbase + it * 256 + wc * 64 + c * 16 + n15] + BIAS;

    uint32 r1[8], r2[8];
    #pragma unroll
    for (int i = 0; i < 8; ++i) { r1[i] = 0xFFFFFFFFu; r2[i] = 0xFFFFFFFFu; }

    // prologue: stage chunks 0,1 (it=0, kc=0,1) into bufs 0,1
    #pragma unroll
    for (int tt = 0; tt < 2; ++tt) {
        gload16(xg + tt * 64, &POOL[tt * 4096 + xdst]);
        #pragma unroll
        for (int j = 0; j < 4; ++j)
            gload16(wg + (size_t)(j * 8) * DIM + tt * 64,
                    &POOL[12288 + tt * 16384 + wdst + j * 512]);
    }
    __syncthreads();   // single full drain; chunks 0,1 resident; w2all retired

    int ic = 0, in_ = 1, ip = 2;   // buf idx of chunks t, t+1, t+2

    #pragma unroll
    for (int it = 0; it < NITER; ++it) {
        f32x4 acc[2][4];
        #pragma unroll
        for (int i = 0; i < 2; ++i)
            #pragma unroll
            for (int c = 0; c < 4; ++c) acc[i][c] = (f32x4){0.f, 0.f, 0.f, 0.f};

        for (int kc = 0; kc < 8; ++kc) {
            const int t = it * 8 + kc;
            // wait own chunk-t loads: only the newest chunk (t+1) may remain
            if (t < 63) asm volatile("s_waitcnt vmcnt(5)" ::: "memory");
            else        asm volatile("s_waitcnt vmcnt(0)" ::: "memory");
            __builtin_amdgcn_s_barrier();          // all waves' t-data in LDS;
            __builtin_amdgcn_sched_barrier(0);     // and compute(t-1) done everywhere

            const u16* X = &POOL[ic * 4096];
            const u16* W = &POOL[12288 + ic * 16384];
            #pragma unroll
            for (int s = 0; s < 2; ++s) {
                const int lq = s * 4 + quad;
                s16x8 af[2], bf[4];
                #pragma unroll
                for (int i = 0; i < 2; ++i) {
                    const int tr = wt * 32 + i * 16 + n15;      // tr&7 == n15&7
                    af[i] = *(const s16x8*)&X[tr * 64 + (lq ^ (tr & 7)) * 8];
                }
                #pragma unroll
                for (int c = 0; c < 4; ++c) {
                    const int cr = wc * 64 + c * 16 + n15;      // cr&7 == n15&7
                    bf[c] = *(const s16x8*)&W[cr * 64 + (lq ^ (cr & 7)) * 8];
                }
                #pragma unroll
                for (int i = 0; i < 2; ++i)
                    #pragma unroll
                    for (int c = 0; c < 4; ++c)
                        acc[i][c] = __builtin_amdgcn_mfma_f32_16x16x32_bf16(af[i], bf[c], acc[i][c], 0, 0, 0);
            }

            // issue chunk t+2 into buf ip (== buf of t-1, barrier-certified free)
            if (t <= 61) {
                const int kcu = (kc + 2) & 7;
                const int itu = it + ((kc + 2) >> 3);
                gload16(xg + kcu * 64, &POOL[ip * 4096 + xdst]);
                const u16* wsrc = wg + (size_t)itu * (256 * DIM) + kcu * 64;
                #pragma unroll
                for (int j = 0; j < 4; ++j)
                    gload16(wsrc + (size_t)(j * 8) * DIM,
                            &POOL[12288 + ip * 16384 + wdst + j * 512]);
            }
            int tmp = ic; ic = in_; in_ = ip; ip = tmp;   // rotate buffers
        }

        // fold this 256-code column into running top-2 per (lane, token-slot)
        #pragma unroll
        for (int i = 0; i < 2; ++i)
            #pragma unroll
            for (int r = 0; r < 4; ++r) {
                const int ti = i * 4 + r;
                #pragma unroll
                for (int c = 0; c < 4; ++c) {
                    float s = fmaf(-2.0f, acc[i][c][r], w2all[it][c]);
                    uint32 key = (__float_as_uint(s) & 0xFFFFFFC0u) | (uint32)((it << 2) | c);
                    uint32 mx = r1[ti] > key ? r1[ti] : key;
                    r1[ti] = r1[ti] < key ? r1[ti] : key;
                    r2[ti] = r2[ti] < mx ? r2[ti] : mx;
                }
            }
    }

    // ------- merge: 64 tokens x 128 entries via LDS, single phase ----------
    __syncthreads();   // all compute done before reusing LDS as MS
    u64* MS = (u64*)POOL;   // 64 tokens x 128 entries = 64 KiB
    #pragma unroll
    for (int ti = 0; ti < 8; ++ti) {
        const int i = ti >> 2, r = ti & 3;
        const int tloc = wt * 32 + i * 16 + quad * 4 + r;    // 0..63
        #pragma unroll
        for (int e = 0; e < 2; ++e) {
            uint32 k  = e ? r2[ti] : r1[ti];
            uint32 vb = k & 0xFFFFFFC0u;
            uint32 id = k & 63u;
            uint32 code = (uint32)(sbase + (id >> 2) * 256 + wc * 64 + (id & 3) * 16 + n15);
            MS[tloc * 128 + (wc * 16 + n15) * 2 + e] = ((u64)vb << 32) | code;
        }
    }
    __syncthreads();
    if (tid < 64) {
        u64 best[6];
        #pragma unroll
        for (int c = 0; c < 6; ++c) best[c] = 0xFFFFFFFFFFFFFFFFull;
        for (int e = 0; e < 128; ++e) {
            u64 v = MS[tid * 128 + e];
            if (v < best[5]) {
                best[5] = v;
                #pragma unroll
                for (int p = 5; p > 0; --p)
                    if (best[p] < best[p - 1]) { u64 tv = best[p]; best[p] = best[p - 1]; best[p - 1] = tv; }
            }
        }
        const int token = m0 + tid;
        u64* dst = candPart + ((size_t)blockIdx.y * N_TOK + token) * 6;
        #pragma unroll
        for (int c = 0; c < 6; ++c) dst[c] = best[c];
    }
}

// ---------------------------------------------------------------------------
// Merge per-split top-6 lists -> global top-NCAND candidate codes per token.
// ---------------------------------------------------------------------------
__global__ __launch_bounds__(256) void mergecand_kernel(const u64* __restrict__ candPart,
                                                        int* __restrict__ candF) {
    int t = blockIdx.x * 256 + threadIdx.x;
    u64 best[NCAND];
    #pragma unroll
    for (int c = 0; c < NCAND; ++c) best[c] = 0xFFFFFFFFFFFFFFFFull;
    for (int s = 0; s < NSPLIT; ++s) {
        const u64* src = candPart + ((size_t)s * N_TOK + t) * 6;
        #pragma unroll
        for (int c = 0; c < 6; ++c) {
            u64 v = src[c];
            if (v < best[NCAND - 1]) {
                best[NCAND - 1] = v;
                #pragma unroll
                for (int p = NCAND - 1; p > 0; --p)
                    if (best[p] < best[p - 1]) { u64 tv = best[p]; best[p] = best[p - 1]; best[p - 1] = tv; }
            }
        }
    }
    #pragma unroll
    for (int c = 0; c < NCAND; ++c) candF[(size_t)t * NCAND + c] = (int)(best[c] & 0xFFFu);
}

// ---------------------------------------------------------------------------
// np-exact refine over NCAND candidates (R3-verified arithmetic).
// ---------------------------------------------------------------------------
__global__ __launch_bounds__(256) void refine_kernel(const float* __restrict__ x,
                                                     const float* __restrict__ w,
                                                     const float* __restrict__ x2np,
                                                     const float* __restrict__ w2np,
                                                     const int* __restrict__ cand,
                                                     int* __restrict__ idx) {
    const int t    = blockIdx.x * 4 + (threadIdx.x >> 6);
    const int lane = threadIdx.x & 63;

    const float* xr = x + (size_t)t * DIM;
    float xv[8];
    #pragma unroll
    for (int j = 0; j < 8; ++j) xv[j] = xr[lane + 64 * j];
    const float x2 = x2np[t];

    float bd = 3.4e38f;
    int   bk = 0x7fffffff;
    for (int c = 0; c < NCAND; ++c) {
        int k = cand[(size_t)t * NCAND + c];
        const float* wr = w + (size_t)k * DIM;
        double m = 0.0;
        #pragma unroll
        for (int j = 0; j < 8; ++j)
            m = fma((double)xv[j], (double)wr[lane + 64 * j], m);
        #pragma unroll
        for (int off = 32; off >= 1; off >>= 1) m += __shfl_down(m, off);
        if (lane == 0) {
            #pragma clang fp contract(off)
            float m32 = (float)m;
            float T1  = x2 + w2np[k];
            float d   = T1 - 2.0f * m32;
            if (d < bd || (d == bd && k < bk)) { bd = d; bk = k; }
        }
    }
    if (lane == 0) idx[t] = bk;
}

// ---------------------------------------------------------------------------
// gather + straight-through output + loss + counts (R3-verified).
// ---------------------------------------------------------------------------
__global__ __launch_bounds__(256) void gather_kernel(const float* __restrict__ x,
                                                     const float* __restrict__ w,
                                                     const int* __restrict__ idx,
                                                     float* __restrict__ out_q,
                                                     float* __restrict__ out_loss,
                                                     float* __restrict__ out_ind,
                                                     int* __restrict__ counts) {
    const int wave = threadIdx.x >> 6;
    const int lane = threadIdx.x & 63;
    const int token = blockIdx.x * 4 + wave;
    const int k = idx[token];

    const float4* xr = (const float4*)(x + (size_t)token * DIM);
    const float4* wr = (const float4*)(w + (size_t)k * DIM);
    float4*       qo = (float4*)(out_q + (size_t)token * DIM);

    float ss = 0.f;
    #pragma unroll
    for (int j = 0; j < 2; ++j) {
        int e = lane + j * 64;
        float4 xv = xr[e];
        float4 wv = wr[e];
        float4 d, o;
        d.x = wv.x - xv.x; o.x = xv.x + d.x;
        d.y = wv.y - xv.y; o.y = xv.y + d.y;
        d.z = wv.z - xv.z; o.z = xv.z + d.z;
        d.w = wv.w - xv.w; o.w = xv.w + d.w;
        ss += d.x * d.x + d.y * d.y + d.z * d.z + d.w * d.w;
        qo[e] = o;
    }
    #pragma unroll
    for (int off = 32; off >= 1; off >>= 1) ss += __shfl_down(ss, off);
    if (lane == 0) {
        float lm = ss * (1.0f / DIM);
        out_loss[token] = lm + COMMIT * lm;
        out_ind[token] = (float)k;
        atomicAdd(&counts[k], 1);
    }
}

// ---------------------------------------------------------------------------
// perplexity (R3-verified).
// ---------------------------------------------------------------------------
__global__ __launch_bounds__(256) void perplex_kernel(const int* __restrict__ counts,
                                                      float* __restrict__ out2) {
    __shared__ double red[4];
    const int tid = threadIdx.x;
    const int lane = tid & 63;
    const int wid = tid >> 6;
    double s = 0.0;
    for (int t = tid; t < K_CODES; t += 256) {
        int c = counts[t];
        if (c) {
            double p = (double)c * (1.0 / N_TOK);
            s += p * log(p + 1e-10);
        }
    }
    #pragma unroll
    for (int off = 32; off >= 1; off >>= 1) s += __shfl_down(s, off);
    if (lane == 0) red[wid] = s;
    __syncthreads();
    if (tid == 0) {
        double t = red[0] + red[1] + red[2] + red[3];
        out2[0] = (float)exp(-t);
    }
}

// ---------------------------------------------------------------------------
extern "C" void kernel_launch(void* const* d_in, const int* in_sizes, int n_in,
                              void* d_out, int out_size, void* d_ws, size_t ws_size,
                              hipStream_t stream) {
    const float* x = (const float*)d_in[0];
    const float* w = (const float*)d_in[1];

    float* out0 = (float*)d_out;                       // quantized_st [N,D]
    float* out1 = out0 + (size_t)N_TOK * DIM;          // loss [N]
    float* out2 = out1 + N_TOK;                        // perplexity [1]
    float* out3 = out2 + 1;                            // indices [N] (as float)

    // workspace layout (8B-aligned chunks first)
    u64*   candPart = (u64*)d_ws;                                 // NSPLIT*N_TOK*6
    float* x2np     = (float*)(candPart + (size_t)NSPLIT * N_TOK * 6);
    float* w2np     = x2np + N_TOK;
    int*   idx      = (int*)(w2np + K_CODES);
    int*   counts   = idx + N_TOK;
    int*   candF    = counts + K_CODES;                           // N_TOK*NCAND
    u16*   x_bf     = (u16*)(candF + (size_t)N_TOK * NCAND);      // N_TOK*DIM
    u16*   w_bf     = x_bf + (size_t)N_TOK * DIM;                 // K_CODES*DIM

    hipMemsetAsync(counts, 0, K_CODES * sizeof(int), stream);

    tobf16_kernel<<<4096, 256, 0, stream>>>(x, x_bf, N_TOK * DIM / 4);
    tobf16_kernel<<<2048, 256, 0, stream>>>(w, w_bf, K_CODES * DIM / 4);
    rowsq_np_kernel<<<N_TOK / 32, 256, 0, stream>>>(x, x2np, N_TOK);
    rowsq_np_kernel<<<K_CODES / 32, 256, 0, stream>>>(w, w2np, K_CODES);
    screen_kernel<<<dim3(N_TOK / 64, NSPLIT), 512, 0, stream>>>(x_bf, w_bf, w2np, candPart);
    mergecand_kernel<<<N_TOK / 256, 256, 0, stream>>>(candPart, candF);
    refine_kernel<<<N_TOK / 4, 256, 0, stream>>>(x, w, x2np, w2np, candF, idx);
    gather_kernel<<<N_TOK / 4, 256, 0, stream>>>(x, w, idx, out0, out1, out3, counts);
    perplex_kernel<<<1, 256, 0, stream>>>(counts, out2);
}

// Round 6
// 471.439 us; speedup vs baseline: 1.0045x; 1.0045x over previous
//
#include <hip/hip_runtime.h>
#include <math.h>

#define N_TOK 32768
#define K_CODES 4096
#define DIM 512
#define COMMIT 0.25f
#define NCAND 8
#define NSPLIT 2
#define SPLIT_CODES (K_CODES / NSPLIT)   // 2048
#define NITER (SPLIT_CODES / 128)        // 16 col-iterations of 128 codes
#define BIAS 0.125f

typedef short s16x8 __attribute__((ext_vector_type(8)));
typedef float f32x4 __attribute__((ext_vector_type(4)));
typedef unsigned int uint32;
typedef unsigned long long u64;
typedef unsigned short u16;

__device__ __forceinline__ u16 f2bf(float f) {
    uint32 b = __float_as_uint(f);
    return (u16)((b + 0x7FFFu + ((b >> 16) & 1u)) >> 16);
}

// global -> LDS direct DMA, 16B per lane. LDS dest wave-uniform; HW writes
// lds + lane*16. Source address is per-lane (pre-swizzled).
__device__ __forceinline__ void gload16(const u16* g, u16* l) {
    __builtin_amdgcn_global_load_lds(
        (const __attribute__((address_space(1))) void*)g,
        (__attribute__((address_space(3))) void*)l,
        16, 0, 0);
}

// ---------------------------------------------------------------------------
// fp32 -> bf16 (RNE) bulk convert.
// ---------------------------------------------------------------------------
__global__ __launch_bounds__(256) void tobf16_kernel(const float* __restrict__ src,
                                                     u16* __restrict__ dst, int n4) {
    int i = blockIdx.x * 256 + threadIdx.x;
    int stride = gridDim.x * 256;
    for (; i < n4; i += stride) {
        float4 v = ((const float4*)src)[i];
        ushort4 o;
        o.x = f2bf(v.x); o.y = f2bf(v.y); o.z = f2bf(v.z); o.w = f2bf(v.w);
        ((ushort4*)dst)[i] = o;
    }
}

// ---------------------------------------------------------------------------
// numpy-exact fp32 row sum of squares (pairwise algorithm) — R3-verified.
// ---------------------------------------------------------------------------
__global__ __launch_bounds__(256) void rowsq_np_kernel(const float* __restrict__ a,
                                                       float* __restrict__ out,
                                                       int nrows) {
    #pragma clang fp contract(off)
    const int gw   = (blockIdx.x * 256 + threadIdx.x) >> 6;
    const int lane = threadIdx.x & 63;
    const int row  = gw * 8 + (lane >> 3);
    const int j    = lane & 7;
    if (row >= nrows) return;
    const float* p = a + (size_t)row * DIM;
    float blk[4];
    #pragma unroll
    for (int b = 0; b < 4; ++b) {
        const float* q = p + b * 128;
        float v = q[j];
        float r = v * v;
        for (int i = 8; i < 128; i += 8) { float u = q[i + j]; r += u * u; }
        float s1 = r  + __shfl_xor(r, 1);
        float s2 = s1 + __shfl_xor(s1, 2);
        float s3 = s2 + __shfl_xor(s2, 4);
        blk[b] = s3;
    }
    float res = (blk[0] + blk[1]) + (blk[2] + blk[3]);
    if (j == 0) out[row] = res;
}

// ---------------------------------------------------------------------------
// MFMA bf16 screen. Block: 512 thr = 8 waves, tile 128 tok x 128 codes/iter
// (NITER=16). Wave tile 64 tok x 32 codes (4x2 grid of 16x16x32 MFMA).
// BK=64 chunks, double-buffered LDS: X 2x16K + W 2x16K = 64 KiB total ->
// 2 blocks/CU (grid 512 = fully co-resident; sibling block hides the
// per-barrier vmcnt drain, m114 mechanism). 128B LDS rows, XOR-swizzled 16B
// quanta (conflict-free reads, R2-verified pattern); DMA = linear LDS dest +
// pre-swizzled per-lane global source quantum (lane&7)^(lane>>3).
// Screening semantics identical to R2-verified: top-2 per 32-code bucket
// {codes ≡ n15 mod 16 within (wc,it) stripe}, id=(it<<1)|c (<32), 128
// entries/token -> top-6 per split. No launch_bounds VGPR cap (R3 lesson).
// ---------------------------------------------------------------------------
__global__ __launch_bounds__(512, 2) void screen_kernel(const u16* __restrict__ xb,
                                                        const u16* __restrict__ wb,
                                                        const float* __restrict__ w2f,
                                                        u64* __restrict__ candPart) {
    __shared__ __attribute__((aligned(16))) u16 POOL[32768];  // 64 KiB
    // u16 units: X0 @0 (8192 = 128 rows x 64), X1 @8192,
    //            W0 @16384 (8192 = 128 rows x 64), W1 @24576.
    // Merge phase reuses all 64 KiB as 64 tok x 128 u64.

    const int tid  = threadIdx.x;
    const int wv   = tid >> 6;
    const int wt   = wv >> 2;          // token half (0/1), 64 rows each
    const int wc   = wv & 3;           // code column (0..3), 32 codes each
    const int lane = tid & 63;
    const int quad = lane >> 4;
    const int n15  = lane & 15;
    const int m0   = blockIdx.x * 128;
    const int sbase = blockIdx.y * SPLIT_CODES;

    // DMA geometry: 1 instr = 64 lanes x 16B = 8 rows x 8 quanta (128B rows).
    // phys quantum p at row r holds logical p^(r&7); r&7 == lane>>3 for
    // 8-aligned row bases -> src quantum = (lane&7)^(lane>>3).
    const int l8  = lane >> 3;
    const int qsw = (lane & 7) ^ l8;

    // X: 128 rows, 16 per wave -> 2 instrs.
    const u16* xg0 = xb + (size_t)(m0 + wv * 16 + l8) * DIM + qsw * 8;
    const u16* xg1 = xg0 + (size_t)8 * DIM;
    // W: 128 rows/chunk, 16 per wave -> 2 instrs; per-it base advances 128 rows.
    const u16* wit = wb + (size_t)(sbase + wv * 16 + l8) * DIM + qsw * 8;

    uint32 r1[16], r2[16];
    #pragma unroll
    for (int i = 0; i < 16; ++i) { r1[i] = 0xFFFFFFFFu; r2[i] = 0xFFFFFFFFu; }

    // prologue: stage it=0 chunk 0 into buffer 0
    {
        u16* lx = &POOL[wv * 1024];
        u16* lw = &POOL[16384 + wv * 1024];
        gload16(xg0, lx);
        gload16(xg1, lx + 512);
        gload16(wit, lw);
        gload16(wit + (size_t)8 * DIM, lw + 512);
    }
    __syncthreads();

    for (int it = 0; it < NITER; ++it) {
        const int nbase = sbase + it * 128;

        float w2pb[2];
        #pragma unroll
        for (int c = 0; c < 2; ++c) w2pb[c] = w2f[nbase + wc * 32 + c * 16 + n15] + BIAS;

        f32x4 acc[4][2];
        #pragma unroll
        for (int i = 0; i < 4; ++i)
            #pragma unroll
            for (int c = 0; c < 2; ++c) acc[i][c] = (f32x4){0.f, 0.f, 0.f, 0.f};

        for (int kc = 0; kc < 8; ++kc) {
            // prefetch chunk kc+1 of this column, or chunk 0 of next column
            if (kc < 7) {
                const int nb = (kc + 1) & 1;
                const int ko = (kc + 1) * 64;
                u16* lx = &POOL[nb * 8192 + wv * 1024];
                u16* lw = &POOL[16384 + nb * 8192 + wv * 1024];
                gload16(xg0 + ko, lx);
                gload16(xg1 + ko, lx + 512);
                gload16(wit + ko, lw);
                gload16(wit + (size_t)8 * DIM + ko, lw + 512);
            } else if (it < NITER - 1) {
                const u16* wn = wit + (size_t)128 * DIM;
                u16* lx = &POOL[wv * 1024];
                u16* lw = &POOL[16384 + wv * 1024];
                gload16(xg0, lx);
                gload16(xg1, lx + 512);
                gload16(wn, lw);
                gload16(wn + (size_t)8 * DIM, lw + 512);
            }

            const u16* X = &POOL[(kc & 1) * 8192];
            const u16* W = &POOL[16384 + (kc & 1) * 8192];
            #pragma unroll
            for (int s = 0; s < 2; ++s) {
                const int lq = s * 4 + quad;
                s16x8 af[4], bf[2];
                #pragma unroll
                for (int i = 0; i < 4; ++i) {
                    const int tr = wt * 64 + i * 16 + n15;      // tr&7 == n15&7
                    af[i] = *(const s16x8*)&X[tr * 64 + (lq ^ (tr & 7)) * 8];
                }
                #pragma unroll
                for (int c = 0; c < 2; ++c) {
                    const int cr = wc * 32 + c * 16 + n15;      // cr&7 == n15&7
                    bf[c] = *(const s16x8*)&W[cr * 64 + (lq ^ (cr & 7)) * 8];
                }
                #pragma unroll
                for (int i = 0; i < 4; ++i)
                    #pragma unroll
                    for (int c = 0; c < 2; ++c)
                        acc[i][c] = __builtin_amdgcn_mfma_f32_16x16x32_bf16(af[i], bf[c], acc[i][c], 0, 0, 0);
            }
            __syncthreads();   // drain -> staged chunk visible (sibling block hides)
        }

        // fold this 128-code column into running top-2 per (lane, token-slot)
        #pragma unroll
        for (int i = 0; i < 4; ++i)
            #pragma unroll
            for (int r = 0; r < 4; ++r) {
                const int ti = i * 4 + r;
                #pragma unroll
                for (int c = 0; c < 2; ++c) {
                    float s = fmaf(-2.0f, acc[i][c][r], w2pb[c]);
                    uint32 key = (__float_as_uint(s) & 0xFFFFFFC0u) | (uint32)((it << 1) | c);
                    uint32 mx = r1[ti] > key ? r1[ti] : key;
                    r1[ti] = r1[ti] < key ? r1[ti] : key;
                    r2[ti] = r2[ti] < mx ? r2[ti] : mx;
                }
            }
        wit += (size_t)128 * DIM;
    }

    // ------- merge: all 128 entries per token via LDS, two phases by wt -----
    u64* MS = (u64*)POOL;   // 64 tokens x 128 entries = 64 KiB
    for (int phase = 0; phase < 2; ++phase) {
        __syncthreads();
        if (wt == phase) {
            #pragma unroll
            for (int ti = 0; ti < 16; ++ti) {
                const int i = ti >> 2, r = ti & 3;
                const int tloc = i * 16 + quad * 4 + r;     // 0..63
                #pragma unroll
                for (int e = 0; e < 2; ++e) {
                    uint32 k  = e ? r2[ti] : r1[ti];
                    uint32 vb = k & 0xFFFFFFC0u;
                    uint32 id = k & 63u;
                    uint32 code = (uint32)(sbase + (id >> 1) * 128 + wc * 32 + (id & 1) * 16 + n15);
                    MS[tloc * 128 + (wc * 16 + n15) * 2 + e] = ((u64)vb << 32) | code;
                }
            }
        }
        __syncthreads();
        if (tid < 64) {
            u64 best[6];
            #pragma unroll
            for (int c = 0; c < 6; ++c) best[c] = 0xFFFFFFFFFFFFFFFFull;
            for (int e = 0; e < 128; ++e) {
                u64 v = MS[tid * 128 + e];
                if (v < best[5]) {
                    best[5] = v;
                    #pragma unroll
                    for (int p = 5; p > 0; --p)
                        if (best[p] < best[p - 1]) { u64 tv = best[p]; best[p] = best[p - 1]; best[p - 1] = tv; }
                }
            }
            const int token = m0 + phase * 64 + tid;
            u64* dst = candPart + ((size_t)blockIdx.y * N_TOK + token) * 6;
            #pragma unroll
            for (int c = 0; c < 6; ++c) dst[c] = best[c];
        }
    }
}

// ---------------------------------------------------------------------------
// Merge per-split top-6 lists -> global top-NCAND candidate codes per token.
// ---------------------------------------------------------------------------
__global__ __launch_bounds__(256) void mergecand_kernel(const u64* __restrict__ candPart,
                                                        int* __restrict__ candF) {
    int t = blockIdx.x * 256 + threadIdx.x;
    u64 best[NCAND];
    #pragma unroll
    for (int c = 0; c < NCAND; ++c) best[c] = 0xFFFFFFFFFFFFFFFFull;
    for (int s = 0; s < NSPLIT; ++s) {
        const u64* src = candPart + ((size_t)s * N_TOK + t) * 6;
        #pragma unroll
        for (int c = 0; c < 6; ++c) {
            u64 v = src[c];
            if (v < best[NCAND - 1]) {
                best[NCAND - 1] = v;
                #pragma unroll
                for (int p = NCAND - 1; p > 0; --p)
                    if (best[p] < best[p - 1]) { u64 tv = best[p]; best[p] = best[p - 1]; best[p - 1] = tv; }
            }
        }
    }
    #pragma unroll
    for (int c = 0; c < NCAND; ++c) candF[(size_t)t * NCAND + c] = (int)(best[c] & 0xFFFu);
}

// ---------------------------------------------------------------------------
// np-exact refine over NCAND candidates (R3-verified arithmetic).
// ---------------------------------------------------------------------------
__global__ __launch_bounds__(256) void refine_kernel(const float* __restrict__ x,
                                                     const float* __restrict__ w,
                                                     const float* __restrict__ x2np,
                                                     const float* __restrict__ w2np,
                                                     const int* __restrict__ cand,
                                                     int* __restrict__ idx) {
    const int t    = blockIdx.x * 4 + (threadIdx.x >> 6);
    const int lane = threadIdx.x & 63;

    const float* xr = x + (size_t)t * DIM;
    float xv[8];
    #pragma unroll
    for (int j = 0; j < 8; ++j) xv[j] = xr[lane + 64 * j];
    const float x2 = x2np[t];

    float bd = 3.4e38f;
    int   bk = 0x7fffffff;
    for (int c = 0; c < NCAND; ++c) {
        int k = cand[(size_t)t * NCAND + c];
        const float* wr = w + (size_t)k * DIM;
        double m = 0.0;
        #pragma unroll
        for (int j = 0; j < 8; ++j)
            m = fma((double)xv[j], (double)wr[lane + 64 * j], m);
        #pragma unroll
        for (int off = 32; off >= 1; off >>= 1) m += __shfl_down(m, off);
        if (lane == 0) {
            #pragma clang fp contract(off)
            float m32 = (float)m;
            float T1  = x2 + w2np[k];
            float d   = T1 - 2.0f * m32;
            if (d < bd || (d == bd && k < bk)) { bd = d; bk = k; }
        }
    }
    if (lane == 0) idx[t] = bk;
}

// ---------------------------------------------------------------------------
// gather + straight-through output + loss + counts (R3-verified).
// ---------------------------------------------------------------------------
__global__ __launch_bounds__(256) void gather_kernel(const float* __restrict__ x,
                                                     const float* __restrict__ w,
                                                     const int* __restrict__ idx,
                                                     float* __restrict__ out_q,
                                                     float* __restrict__ out_loss,
                                                     float* __restrict__ out_ind,
                                                     int* __restrict__ counts) {
    const int wave = threadIdx.x >> 6;
    const int lane = threadIdx.x & 63;
    const int token = blockIdx.x * 4 + wave;
    const int k = idx[token];

    const float4* xr = (const float4*)(x + (size_t)token * DIM);
    const float4* wr = (const float4*)(w + (size_t)k * DIM);
    float4*       qo = (float4*)(out_q + (size_t)token * DIM);

    float ss = 0.f;
    #pragma unroll
    for (int j = 0; j < 2; ++j) {
        int e = lane + j * 64;
        float4 xv = xr[e];
        float4 wv = wr[e];
        float4 d, o;
        d.x = wv.x - xv.x; o.x = xv.x + d.x;
        d.y = wv.y - xv.y; o.y = xv.y + d.y;
        d.z = wv.z - xv.z; o.z = xv.z + d.z;
        d.w = wv.w - xv.w; o.w = xv.w + d.w;
        ss += d.x * d.x + d.y * d.y + d.z * d.z + d.w * d.w;
        qo[e] = o;
    }
    #pragma unroll
    for (int off = 32; off >= 1; off >>= 1) ss += __shfl_down(ss, off);
    if (lane == 0) {
        float lm = ss * (1.0f / DIM);
        out_loss[token] = lm + COMMIT * lm;
        out_ind[token] = (float)k;
        atomicAdd(&counts[k], 1);
    }
}

// ---------------------------------------------------------------------------
// perplexity (R3-verified).
// ---------------------------------------------------------------------------
__global__ __launch_bounds__(256) void perplex_kernel(const int* __restrict__ counts,
                                                      float* __restrict__ out2) {
    __shared__ double red[4];
    const int tid = threadIdx.x;
    const int lane = tid & 63;
    const int wid = tid >> 6;
    double s = 0.0;
    for (int t = tid; t < K_CODES; t += 256) {
        int c = counts[t];
        if (c) {
            double p = (double)c * (1.0 / N_TOK);
            s += p * log(p + 1e-10);
        }
    }
    #pragma unroll
    for (int off = 32; off >= 1; off >>= 1) s += __shfl_down(s, off);
    if (lane == 0) red[wid] = s;
    __syncthreads();
    if (tid == 0) {
        double t = red[0] + red[1] + red[2] + red[3];
        out2[0] = (float)exp(-t);
    }
}

// ---------------------------------------------------------------------------
extern "C" void kernel_launch(void* const* d_in, const int* in_sizes, int n_in,
                              void* d_out, int out_size, void* d_ws, size_t ws_size,
                              hipStream_t stream) {
    const float* x = (const float*)d_in[0];
    const float* w = (const float*)d_in[1];

    float* out0 = (float*)d_out;                       // quantized_st [N,D]
    float* out1 = out0 + (size_t)N_TOK * DIM;          // loss [N]
    float* out2 = out1 + N_TOK;                        // perplexity [1]
    float* out3 = out2 + 1;                            // indices [N] (as float)

    // workspace layout (8B-aligned chunks first)
    u64*   candPart = (u64*)d_ws;                                 // NSPLIT*N_TOK*6
    float* x2np     = (float*)(candPart + (size_t)NSPLIT * N_TOK * 6);
    float* w2np     = x2np + N_TOK;
    int*   idx      = (int*)(w2np + K_CODES);
    int*   counts   = idx + N_TOK;
    int*   candF    = counts + K_CODES;                           // N_TOK*NCAND
    u16*   x_bf     = (u16*)(candF + (size_t)N_TOK * NCAND);      // N_TOK*DIM
    u16*   w_bf     = x_bf + (size_t)N_TOK * DIM;                 // K_CODES*DIM

    hipMemsetAsync(counts, 0, K_CODES * sizeof(int), stream);

    tobf16_kernel<<<4096, 256, 0, stream>>>(x, x_bf, N_TOK * DIM / 4);
    tobf16_kernel<<<2048, 256, 0, stream>>>(w, w_bf, K_CODES * DIM / 4);
    rowsq_np_kernel<<<N_TOK / 32, 256, 0, stream>>>(x, x2np, N_TOK);
    rowsq_np_kernel<<<K_CODES / 32, 256, 0, stream>>>(w, w2np, K_CODES);
    screen_kernel<<<dim3(N_TOK / 128, NSPLIT), 512, 0, stream>>>(x_bf, w_bf, w2np, candPart);
    mergecand_kernel<<<N_TOK / 256, 256, 0, stream>>>(candPart, candF);
    refine_kernel<<<N_TOK / 4, 256, 0, stream>>>(x, w, x2np, w2np, candF, idx);
    gather_kernel<<<N_TOK / 4, 256, 0, stream>>>(x, w, idx, out0, out1, out3, counts);
    perplex_kernel<<<1, 256, 0, stream>>>(counts, out2);
}